// Round 7
// baseline (633.229 us; speedup 1.0000x reference)
//
#include <hip/hip_runtime.h>

typedef __attribute__((ext_vector_type(8))) short bf16x8;
typedef __attribute__((ext_vector_type(4))) float f32x4;
typedef __attribute__((ext_vector_type(4))) uint  u32x4;
typedef __attribute__((ext_vector_type(2))) uint  u32x2;

// Problem constants
#define B_   16
#define C_   64
#define H_   64
#define W_   64
#define HD_  128
#define K_   320      // C + 2*HD
#define SW_  127      // H+W-1

// Decomposition: 4 hd-groups (32 hd each) x 64 col-clusters (16 cols each) = 256 blocks
#define NG    4
#define GH    32      // hd per group
#define NCG   64      // clusters
#define TC    16      // cols per cluster
#define NT    768     // 12 waves: 0-9 GEMM (0-7 nonlin, 8-9 x-build), 10-11 aux pollers
#define ROWS  160     // gate rows per block (5 gates x 32 hd)
#define NKT   10      // K/32 k-tiles
#define GPS   17      // gate-panel stride

// Workspace layout (float/uint offsets).
// h ring: 4 slots x 1024 cols x 128 hd, fp32 with pass-parity tag in the
// mantissa LSB (2^-24, numerically free). Per-word tags: data is its own
// flag; RAW chain = store -> poll-hit (1 MALL hop). Prep wipes rings to
// tag=1 (pass -1) so pass-0 polls can't accept residue.
#define HSLOT  131072LL
#define CBX    524288LL                    // c boundary ring: 4 x NCG x NG x GH
#define CNT    557056LL                    // (legacy region, zeroed)
#define GCNT   559104LL                    // 64 WAR tokens, stride 32 ints
#define AFB    561152LL                    // A-fragments: 204800 floats (hi+lo bf16)
#define AF_N   204800LL
#define XT     765952LL                    // xT[b][hr][w][c]
#define XT_N   4194304LL
#define WS_MIN (AFB + AF_N)
#define WS_XT  (XT + XT_N)

#define POLL_CAP (1 << 20)   // safety: a protocol bug fails absmax instead of hanging

__device__ __forceinline__ float sigm(float v) { return 1.f / (1.f + __expf(-v)); }
__device__ __forceinline__ float tanh_fast(float v) {
    float e = __expf(2.f * v);
    return 1.f - 2.f / (e + 1.f);
}

__device__ __forceinline__ int rload(int* p) {
    return __hip_atomic_load(p, __ATOMIC_RELAXED, __HIP_MEMORY_SCOPE_AGENT);
}
__device__ __forceinline__ void rbump(int* p) {
    __hip_atomic_fetch_add(p, 1, __ATOMIC_RELAXED, __HIP_MEMORY_SCOPE_AGENT);
}
__device__ __forceinline__ void wait_ge(int* p, int tgt) {
    int guard = 0;
    while (rload(p) < tgt) { if (++guard > POLL_CAP) break; }
    __atomic_signal_fence(__ATOMIC_ACQUIRE);
}

// Coherence-point (sc0 sc1) ops: bypass L1/L2; weights/xT stay L2-warm.
__device__ __forceinline__ void stu_nw(uint* p, uint v) {     // fire-and-forget
    asm volatile("global_store_dword %0, %1, off sc0 sc1" :: "v"(p), "v"(v) : "memory");
}
__device__ __forceinline__ void st2_nw(uint* p, u32x2 v) {    // paired store
    asm volatile("global_store_dwordx2 %0, %1, off sc0 sc1" :: "v"(p), "v"(v) : "memory");
}

// Poll one 16B chunk until every 32-bit word's LSB == want.
__device__ __forceinline__ void poll1(const uint* p, uint want, u32x4& A) {
    int guard = 0;
    while (true) {
        u32x4 a;
        asm volatile("global_load_dwordx4 %0, %1, off sc0 sc1\n\ts_waitcnt vmcnt(0)"
                     : "=&v"(a) : "v"(p) : "memory");
        uint m = a[0] & a[1] & a[2] & a[3];
        uint o = a[0] | a[1] | a[2] | a[3];
        bool ok = want ? ((m & 1u) != 0u) : ((o & 1u) == 0u);
        if (ok || ++guard > POLL_CAP) { A = a; return; }
    }
}

// Batched 8x dwordx4 poll attempt over one lane's 32 h values (4 kt x 8 jj,
// quad fixed). Offsets: kt-major pairs {0,16,128,144,256,272,384,400} bytes.
__device__ __forceinline__ bool try8(const uint* p, uint want,
                                     u32x4& a0, u32x4& a1, u32x4& a2, u32x4& a3,
                                     u32x4& a4, u32x4& a5, u32x4& a6, u32x4& a7) {
    asm volatile(
        "global_load_dwordx4 %0, %8, off sc0 sc1\n\t"
        "global_load_dwordx4 %1, %8, off offset:16 sc0 sc1\n\t"
        "global_load_dwordx4 %2, %8, off offset:128 sc0 sc1\n\t"
        "global_load_dwordx4 %3, %8, off offset:144 sc0 sc1\n\t"
        "global_load_dwordx4 %4, %8, off offset:256 sc0 sc1\n\t"
        "global_load_dwordx4 %5, %8, off offset:272 sc0 sc1\n\t"
        "global_load_dwordx4 %6, %8, off offset:384 sc0 sc1\n\t"
        "global_load_dwordx4 %7, %8, off offset:400 sc0 sc1\n\t"
        "s_waitcnt vmcnt(0)"
        : "=&v"(a0), "=&v"(a1), "=&v"(a2), "=&v"(a3),
          "=&v"(a4), "=&v"(a5), "=&v"(a6), "=&v"(a7)
        : "v"(p) : "memory");
    uint m = a0[0] & a0[1] & a0[2] & a0[3] & a1[0] & a1[1] & a1[2] & a1[3]
           & a2[0] & a2[1] & a2[2] & a2[3] & a3[0] & a3[1] & a3[2] & a3[3]
           & a4[0] & a4[1] & a4[2] & a4[3] & a5[0] & a5[1] & a5[2] & a5[3]
           & a6[0] & a6[1] & a6[2] & a6[3] & a7[0] & a7[1] & a7[2] & a7[3];
    uint o = a0[0] | a0[1] | a0[2] | a0[3] | a1[0] | a1[1] | a1[2] | a1[3]
           | a2[0] | a2[1] | a2[2] | a2[3] | a3[0] | a3[1] | a3[2] | a3[3]
           | a4[0] | a4[1] | a4[2] | a4[3] | a5[0] | a5[1] | a5[2] | a5[3]
           | a6[0] | a6[1] | a6[2] | a6[3] | a7[0] | a7[1] | a7[2] | a7[3];
    return want ? ((m & 1u) != 0u) : ((o & 1u) == 0u);
}

__device__ __forceinline__ uint bf16hi(uint u) { return (u + 0x7FFFu + ((u >> 16) & 1u)) >> 16; }
__device__ __forceinline__ uint2 splitbf(float v) {
    uint uh = bf16hi(__float_as_uint(v));
    float rl = v - __uint_as_float(uh << 16);
    uint ul = bf16hi(__float_as_uint(rl));
    return make_uint2(uh, ul);
}

// ---------------------------------------------------------------------------
// Prep: wipe rings to tag=1 (0x00000001); zero counters; build A-fragments
// (split-bf16, MFMA lane order).
// ---------------------------------------------------------------------------
__global__ void lstm_prep(const float* __restrict__ w_is,
                          const float* __restrict__ w_ss,
                          float* __restrict__ ws, long long n_ws)
{
    const long long stride = (long long)gridDim.x * blockDim.x;
    const long long t0 = (long long)blockIdx.x * blockDim.x + threadIdx.x;
    uint* wsu = (uint*)ws;

    for (long long i = t0; i < 524288LL + 32768LL; i += stride) {
        long long a = (i < 524288LL) ? i : (CBX + (i - 524288LL));
        stu_nw(wsu + a, 0x00000001u);
    }
    for (long long i = CNT + t0; i < CNT + 4096; i += stride)
        stu_nw(wsu + i, 0u);

    if (n_ws >= WS_MIN) {
        ushort* af = (ushort*)(ws + AFB);
        for (long long e = t0; e < AF_N; e += stride) {
            int idx   = (int)e;
            int chunk = idx >> 9;           // (g*NRT+rt)*NKT + kt
            int lane  = (idx >> 3) & 63;
            int jj    = idx & 7;
            int g  = chunk / (10 * NKT);
            int rm = chunk % (10 * NKT);
            int rt = rm / NKT, kt = rm % NKT;
            int m = lane & 15, quad = lane >> 4;
            int r = rt * 16 + m;
            int q = r >> 5, hl = r & 31;
            int o = q * HD_ + g * GH + hl;
            int k = kt * 32 + quad * 8 + jj;
            float v;
            if (k < C_)            v = w_is[o * C_ + k];
            else if (k < C_ + HD_) v = w_ss[(o * HD_ + (k - C_)) * 2 + 1];
            else                   v = w_ss[(o * HD_ + (k - C_ - HD_)) * 2 + 0];
            uint uh = bf16hi(__float_as_uint(v));
            float rl = v - __uint_as_float(uh << 16);
            uint ul = bf16hi(__float_as_uint(rl));
            int base = chunk * 1024 + lane * 16 + jj;   // ushort units
            af[base]     = (ushort)uh;
            af[base + 8] = (ushort)ul;
        }
    }
}

// ---------------------------------------------------------------------------
// Coalesced transpose: x[b][c][hr][w] -> xT[b][hr][w][c] via 64x64 LDS tile.
// ---------------------------------------------------------------------------
__global__ void lstm_xpose(const float* __restrict__ x, float* __restrict__ ws)
{
    __shared__ float L[64 * 65];
    const int b = blockIdx.x >> 6, hr = blockIdx.x & 63;
    const int tid = threadIdx.x;          // 256 threads
    #pragma unroll
    for (int it = 0; it < 16; ++it) {
        int c = it * 4 + (tid >> 6), w = tid & 63;
        L[c * 65 + w] = x[(((size_t)b * C_ + c) * H_ + hr) * W_ + w];
    }
    __syncthreads();
    float* xt = ws + XT;
    #pragma unroll
    for (int it = 0; it < 16; ++it) {
        int w = it * 4 + (tid >> 6), c = tid & 63;
        xt[(((size_t)b * H_ + hr) * W_ + w) * C_ + c] = L[c * 65 + w];
    }
}

// ---------------------------------------------------------------------------
// Persistent kernel: 127 diagonal steps, self-tagged dataflow with ROLE-SPLIT
// waves: per iteration {sync_a -> GEMM (waves 0-9) -> sync_b -> post-phase:
// nonlin+stores (waves 0-7) || x-build j+1 (waves 8-9) || h-poll j+1 + convert
// (wave 10: 16 cols x 128B rows; wave 11: boundary col + c-poll + WAR)}.
// Aux pollers spin while producers run nonlin -> exchange latency hides under
// compute. GEMM uses 4 independent accumulator chains.
// ---------------------------------------------------------------------------
__global__ void __launch_bounds__(NT, 3) lstm_persist(
    const float* __restrict__ x,
    const float* __restrict__ ws_c,
    const float* __restrict__ b_is,
    const float* __restrict__ b_ss,
    float* __restrict__ out,
    float* __restrict__ ws,
    int use_xt)
{
    __shared__ uint  Bf[NKT * 576];     // B-fragments: per kt, 64 lanes x (16B hi + 16B lo)
    __shared__ float Gp[ROWS * GPS];    // gate panel
    __shared__ float Cs[2][17 * GH];    // double-buffered c panel [colp][hl]
    __shared__ float bias_s[ROWS];

    const int tid = threadIdx.x;
    const int cgp = blockIdx.x >> 2;
    const int g   = blockIdx.x & 3;
    const int n0  = cgp * TC;
    const int inb  = (n0 & 63) != 0;
    const int hasr = ((n0 + TC) & 63) != 0;

    uint* hring = (uint*)ws;
    uint* cring = (uint*)(ws + CBX);
    int*  gcntp = (int*)(ws + GCNT);
    const float* xt = ws_c + XT;
    const uint4* afq = (const uint4*)(ws_c + AFB);

    if (tid < ROWS) {
        int q = tid >> 5, hl = tid & 31;
        int o = q * HD_ + g * GH + hl;
        bias_s[tid] = b_is[o] + b_ss[o];
    }
    if (tid < 17 * GH) Cs[0][tid] = 0.f;    // step-0 c panel
    if (tid >= 544 && tid < 544 + GH) Cs[1][tid - 544] = 0.f;   // boundary col, buf 1

    const int lane = tid & 63;
    const int wv   = tid >> 6;          // waves 0-9 = GEMM row-tiles
    const int quad = lane >> 4;
    const int colc = lane & 15;
    uint* bfr = &Bf[lane * 8 + ((lane >> 2) << 2)];   // GEMM read base

    // ---- x-build constants (waves 8-9, tid 512-639) ----
    const int xi = tid - 512;
    const int xkt = (xi >> 6) & 1, xl = xi & 63;
    const int xq = xl >> 4, xcolc = xl & 15;
    const int xc0 = xkt * 32 + xq * 8;
    const int xn = n0 + xcolc, xb = xn >> 6, xhr = xn & 63;
    uint* bfX = &Bf[xl * 8 + ((xl >> 2) << 2) + xkt * 576];

    // ---- wave-10 h-poll constants: lane pl covers col16 = pl>>2, quad sub = pl&3,
    //      32 h values (4 kt x 8 jj) from a contiguous 128B row segment ----
    const int pl    = tid - 640;
    const int col16 = (pl >> 2) & 15;
    const int sub   = pl & 3;
    const int laneT = sub * 16 + col16;          // unshifted tiles (kt 2-5)
    const int laneS = sub * 16 + col16 + 1;      // shifted tiles (kt 6-9), col16<=14
    uint* pA = &Bf[laneT * 8 + ((laneT >> 2) << 2)];
    uint* pB = &Bf[laneS * 8 + ((laneS >> 2) << 2)];
    const uint* hb10 = hring + (size_t)(n0 + col16) * 128 + sub * 8;

    // ---- wave-11 constants: lanes 0-31 boundary col poll, 32-39 c-poll, 40 WAR ----
    const int ql = tid - 704;
    const int bkt  = 6 + ((ql >> 3) & 3);
    const int bquad = (ql >> 1) & 3;
    const int bj0h = (ql & 1) * 2;               // uint offset within hi/lo rows
    const int laneB0 = bquad * 16;               // shifted col 0
    uint* pC = &Bf[laneB0 * 8 + ((laneB0 >> 2) << 2) + bkt * 576 + bj0h];
    const uint* hb11 = hring + (size_t)(n0 - 1) * 128 + (ql & 31) * 4;
    const int ci = ql - 32;                      // 0..7 c-poll

    // ---- A hi AND lo fragments pinned in registers (GEMM waves only) ----
    bf16x8 Ahr[NKT], Alr[NKT];
    if (wv < 10) {
        const uint4* ap0 = afq + (size_t)((g * 10 + wv) * NKT) * 128 + lane * 2;
        #pragma unroll
        for (int kt = 0; kt < NKT; ++kt) {
            uint4 ha = ap0[kt * 128];
            Ahr[kt] = *(bf16x8*)&ha;
            asm volatile("" : "+v"(Ahr[kt]));
            uint4 la = ap0[kt * 128 + 1];
            Alr[kt] = *(bf16x8*)&la;
            asm volatile("" : "+v"(Alr[kt]));
        }
    }

#define XBUILD(JJ)                                                              \
    {                                                                           \
        float xv[8];                                                            \
        int w = (JJ) - xhr;                                                     \
        if ((unsigned)w < (unsigned)W_) {                                       \
            if (use_xt) {                                                       \
                const float* xp = xt + (((size_t)xb * H_ + xhr) * W_ + w) * C_ + xc0; \
                f32x4 va = *(const f32x4*)xp, vb = *(const f32x4*)(xp + 4);     \
                _Pragma("unroll")                                               \
                for (int r = 0; r < 4; ++r) { xv[r] = va[r]; xv[4 + r] = vb[r]; } \
            } else {                                                            \
                _Pragma("unroll")                                               \
                for (int r = 0; r < 8; ++r)                                     \
                    xv[r] = x[(((size_t)xb * C_ + xc0 + r) * H_ + xhr) * W_ + w]; \
            }                                                                   \
        } else {                                                                \
            _Pragma("unroll")                                                   \
            for (int r = 0; r < 8; ++r) xv[r] = 0.f;                            \
        }                                                                       \
        uint hw[4], lw[4];                                                      \
        _Pragma("unroll")                                                       \
        for (int p = 0; p < 4; ++p) {                                           \
            uint2 e0 = splitbf(xv[2 * p]), e1 = splitbf(xv[2 * p + 1]);         \
            hw[p] = e0.x | (e1.x << 16);                                        \
            lw[p] = e0.y | (e1.y << 16);                                        \
        }                                                                       \
        *(uint4*)bfX       = make_uint4(hw[0], hw[1], hw[2], hw[3]);            \
        *(uint4*)(bfX + 4) = make_uint4(lw[0], lw[1], lw[2], lw[3]);            \
    }

#define FRAG(MM, CA, CB)                                                        \
    {                                                                           \
        uint2 e0 = splitbf(__uint_as_float(CA[0])), e1 = splitbf(__uint_as_float(CA[1])); \
        uint2 e2 = splitbf(__uint_as_float(CA[2])), e3 = splitbf(__uint_as_float(CA[3])); \
        uint2 f0 = splitbf(__uint_as_float(CB[0])), f1 = splitbf(__uint_as_float(CB[1])); \
        uint2 f2 = splitbf(__uint_as_float(CB[2])), f3 = splitbf(__uint_as_float(CB[3])); \
        uint4 hi4 = make_uint4(e0.x | (e1.x << 16), e2.x | (e3.x << 16),        \
                               f0.x | (f1.x << 16), f2.x | (f3.x << 16));       \
        uint4 lo4 = make_uint4(e0.y | (e1.y << 16), e2.y | (e3.y << 16),        \
                               f0.y | (f1.y << 16), f2.y | (f3.y << 16));       \
        *(uint4*)(pA + (2 + (MM)) * 576)     = hi4;                             \
        *(uint4*)(pA + (2 + (MM)) * 576 + 4) = lo4;                             \
        if (col16 <= 14) {                                                      \
            *(uint4*)(pB + (6 + (MM)) * 576)     = hi4;                         \
            *(uint4*)(pB + (6 + (MM)) * 576 + 4) = lo4;                         \
        }                                                                       \
    }

    // ---- pre-phase: populate Bf for step 0 (x real; h fragments zero) ----
    if (wv == 8 || wv == 9) {
        XBUILD(0)
    } else if (wv == 10) {
        uint4 z = make_uint4(0, 0, 0, 0);
        #pragma unroll
        for (int m = 0; m < 4; ++m) {
            *(uint4*)(pA + (2 + m) * 576) = z;  *(uint4*)(pA + (2 + m) * 576 + 4) = z;
            if (col16 <= 14) {
                *(uint4*)(pB + (6 + m) * 576) = z;  *(uint4*)(pB + (6 + m) * 576 + 4) = z;
            }
        }
    } else if (wv == 11 && ql < 32) {
        u32x2 z2 = {0, 0};
        *(u32x2*)pC = z2;  *(u32x2*)(pC + 4) = z2;
    }

    for (int j = 0; j < SW_; ++j) {
        __syncthreads();                         // sync_a: Bf_j / Cs[j&1] ready
        if (tid == 0) rbump(gcntp + cgp * 32);   // h_{j-1}/c_{j-1} consumed

        // ---- GEMM: rows [wv*16,+16) x 16 cols, K=320, 4 acc chains ----
        if (wv < 10) {
            f32x4 aA = {0.f, 0.f, 0.f, 0.f};
            f32x4 aB = {0.f, 0.f, 0.f, 0.f};
            f32x4 aC = {0.f, 0.f, 0.f, 0.f};
            f32x4 aD = {0.f, 0.f, 0.f, 0.f};
            __builtin_amdgcn_s_setprio(1);
            #pragma unroll
            for (int kt = 0; kt < NKT; ++kt) {
                const uint* bp = bfr + kt * 576;
                uint4 hb = *(const uint4*)bp;
                uint4 lb = *(const uint4*)(bp + 4);
                bf16x8 Bh = *(bf16x8*)&hb, Bl = *(bf16x8*)&lb;
                aA = __builtin_amdgcn_mfma_f32_16x16x32_bf16(Ahr[kt], Bh, aA, 0, 0, 0);
                aB = __builtin_amdgcn_mfma_f32_16x16x32_bf16(Ahr[kt], Bl, aB, 0, 0, 0);
                aC = __builtin_amdgcn_mfma_f32_16x16x32_bf16(Alr[kt], Bh, aC, 0, 0, 0);
                aD = __builtin_amdgcn_mfma_f32_16x16x32_bf16(Alr[kt], Bl, aD, 0, 0, 0);
            }
            __builtin_amdgcn_s_setprio(0);
            #pragma unroll
            for (int r = 0; r < 4; ++r)
                Gp[(wv * 16 + quad * 4 + r) * GPS + colc] = (aA[r] + aB[r]) + (aC[r] + aD[r]);
        }
        __syncthreads();                         // sync_b: gates ready, Bf free

        // ================= post-phase (concurrent roles) =================
        const uint wtag = (j >> 2) & 1u;         // tag of step-j data

        if (tid < GH * TC) {
            // ---- waves 0-7: nonlinearity + state + tagged ring stores ----
            const int hl = tid & 31, col = tid >> 5;
            int n = n0 + col, b = n >> 6, hr = n & 63;
            float go  = Gp[(0 * GH + hl) * GPS + col] + bias_s[0 * GH + hl];
            float gfl = Gp[(1 * GH + hl) * GPS + col] + bias_s[1 * GH + hl];
            float gfu = Gp[(2 * GH + hl) * GPS + col] + bias_s[2 * GH + hl];
            float gi  = Gp[(3 * GH + hl) * GPS + col] + bias_s[3 * GH + hl];
            float gg  = Gp[(4 * GH + hl) * GPS + col] + bias_s[4 * GH + hl];
            float so = sigm(go), sfl = sigm(gfl), sfu = sigm(gfu), si = sigm(gi);
            float tg = tanh_fast(gg);
            float cp_ = Cs[j & 1][(col + 1) * GH + hl];
            float cs = Cs[j & 1][col * GH + hl];
            float cv = sfl * cp_ + sfu * cs + si * tg;
            float hv = so * tanh_fast(cv);
            Cs[(j + 1) & 1][(col + 1) * GH + hl] = cv;   // disjoint from boundary [0,32)

            uint pk = (__float_as_uint(hv) & ~1u) | wtag;   // tag in fp32 LSB: 2^-24
            uint other = (uint)__shfl_xor((int)pk, 1);
            if (!(hl & 1)) {                                // paired store: 2 hd per req
                u32x2 pv = {pk, other};
                st2_nw(hring + (size_t)(j & 3) * HSLOT + (size_t)n * 128 + g * GH + (hl & ~1), pv);
            }
            if (col == TC - 1) {
                uint cpk = (__float_as_uint(cv) & ~1u) | wtag;
                stu_nw(cring + (((size_t)(j & 3) * NCG + cgp) * NG + g) * GH + hl, cpk);
            }
            int w = j - hr;
            if ((unsigned)w < (unsigned)W_)
                out[(((size_t)b * HD_ + g * GH + hl) * H_ + hr) * W_ + w] = hv;
        } else if (wv == 8 || wv == 9) {
            // ---- x fragments for step j+1 (Bf kt 0-1) ----
            if (j + 1 < SW_) { XBUILD(j + 1) }
        } else if (wv == 10) {
            // ---- poll h_j (cols n0..n0+15) and build kt 2-9 fragments ----
            if (j + 1 < SW_) {
                const uint* p = hb10 + (size_t)(j & 3) * HSLOT;
                u32x4 a0, a1, a2, a3, a4, a5, a6, a7;
                int guard = 0;
                while (!try8(p, wtag, a0, a1, a2, a3, a4, a5, a6, a7)) {
                    if (++guard > POLL_CAP) break;
                }
                FRAG(0, a0, a1)
                FRAG(1, a2, a3)
                FRAG(2, a4, a5)
                FRAG(3, a6, a7)
            }
        } else {
            // ---- wave 11: boundary col poll / c-poll / WAR token ----
            if (ql < 32) {
                if (j + 1 < SW_ && inb) {
                    u32x4 a;
                    poll1(hb11 + (size_t)(j & 3) * HSLOT, wtag, a);
                    uint2 e0 = splitbf(__uint_as_float(a[0]));
                    uint2 e1 = splitbf(__uint_as_float(a[1]));
                    uint2 e2 = splitbf(__uint_as_float(a[2]));
                    uint2 e3 = splitbf(__uint_as_float(a[3]));
                    u32x2 hp = {e0.x | (e1.x << 16), e2.x | (e3.x << 16)};
                    u32x2 lp = {e0.y | (e1.y << 16), e2.y | (e3.y << 16)};
                    *(u32x2*)pC = hp;  *(u32x2*)(pC + 4) = lp;
                }
            } else if (ci >= 0 && ci < 8) {
                if (j + 1 < SW_ && inb) {        // c boundary for step j+1
                    u32x4 cv4;
                    const uint* cpx = cring +
                        (((size_t)(j & 3) * NCG + (cgp - 1)) * NG + g) * GH + ci * 4;
                    poll1(cpx, wtag, cv4);
                    #pragma unroll
                    for (int r = 0; r < 4; ++r)
                        Cs[(j + 1) & 1][ci * 4 + r] = __uint_as_float(cv4[r]);
                }
            } else if (ci == 8) {
                // WAR: before nonlin_{j+1} overwrites slot (j+1)&3 (= h_{j-3}),
                // right cluster must have consumed h_{j-3} (gcnt >= 4*(j-1)).
                if (j >= 3 && j + 1 < SW_ && hasr)
                    wait_ge(gcntp + (cgp + 1) * 32, 4 * (j - 1));
            }
        }
    }
#undef XBUILD
#undef FRAG
}

// ---------------------------------------------------------------------------
extern "C" void kernel_launch(void* const* d_in, const int* in_sizes, int n_in,
                              void* d_out, int out_size, void* d_ws, size_t ws_size,
                              hipStream_t stream)
{
    const float* x    = (const float*)d_in[0];
    const float* w_is = (const float*)d_in[1];
    const float* b_is = (const float*)d_in[2];
    const float* w_ss = (const float*)d_in[3];
    const float* b_ss = (const float*)d_in[4];
    float* out = (float*)d_out;
    float* ws  = (float*)d_ws;

    const long long n_ws = (long long)(ws_size / 4);
    const int use_xt = (n_ws >= WS_XT) ? 1 : 0;

    hipLaunchKernelGGL(lstm_prep, dim3(1024), dim3(256), 0, stream,
                       w_is, w_ss, ws, n_ws);
    if (use_xt)
        hipLaunchKernelGGL(lstm_xpose, dim3(B_ * H_), dim3(256), 0, stream, x, ws);

    hipLaunchKernelGGL(lstm_persist, dim3(NG * NCG), dim3(NT), 0, stream,
                       x, ws, b_is, b_ss, out, ws, use_xt);
}

// Round 8
// 492.423 us; speedup vs baseline: 1.2859x; 1.2859x over previous
//
#include <hip/hip_runtime.h>

typedef __attribute__((ext_vector_type(8))) short bf16x8;
typedef __attribute__((ext_vector_type(4))) float f32x4;
typedef __attribute__((ext_vector_type(4))) uint  u32x4;
typedef __attribute__((ext_vector_type(2))) uint  u32x2;

// Problem constants
#define B_   16
#define C_   64
#define H_   64
#define W_   64
#define HD_  128
#define K_   320      // C + 2*HD
#define SW_  127      // H+W-1

// Decomposition: 4 hd-groups (32 hd each) x 64 col-clusters (16 cols each) = 256 blocks
#define NG    4
#define GH    32      // hd per group
#define NCG   64      // clusters
#define TC    16      // cols per cluster
#define NT    704     // threads per block (11 waves: 10 GEMM + 1 aux)
#define ROWS  160     // gate rows per block (5 gates x 32 hd)
#define NKT   10      // K/32 k-tiles
#define GPS   17      // gate-panel stride

// Workspace layout (float/uint offsets).
// h ring: 4 slots x 1024 cols x 128 hd, fp32 with pass-parity tag in the
// mantissa LSB (2^-24, numerically free). Per-word tags: data is its own
// flag, RAW chain = store -> poll-hit. Ring ops use DEVICE scope (sc1 only):
// bypass L1 + per-XCD L2, CACHE IN THE MALL. Round-6 used sc0+sc1 = SYSTEM
// scope, which bypasses the Infinity Cache -> every poll/store was a ~900cy
// DRAM roundtrip (FETCH_SIZE 174MB/dispatch = polled window missing to HBM).
// Prep wipes rings to tag=1 (pass -1) so pass-0 polls can't accept residue.
#define HSLOT  131072LL
#define CBX    524288LL                    // c boundary ring: 4 x NCG x NG x GH
#define CNT    557056LL                    // (legacy region, zeroed)
#define GCNT   559104LL                    // 64 WAR tokens, stride 32 ints
#define AFB    561152LL                    // A-fragments: 204800 floats (hi+lo bf16)
#define AF_N   204800LL
#define XT     765952LL                    // xT[b][hr][w][c]
#define XT_N   4194304LL
#define WS_MIN (AFB + AF_N)
#define WS_XT  (XT + XT_N)

#define POLL_CAP (1 << 20)   // safety: a protocol bug fails absmax instead of hanging

__device__ __forceinline__ float sigm(float v) { return 1.f / (1.f + __expf(-v)); }
__device__ __forceinline__ float tanh_fast(float v) {
    float e = __expf(2.f * v);
    return 1.f - 2.f / (e + 1.f);
}

__device__ __forceinline__ int rload(int* p) {
    return __hip_atomic_load(p, __ATOMIC_RELAXED, __HIP_MEMORY_SCOPE_AGENT);
}
__device__ __forceinline__ void rbump(int* p) {
    __hip_atomic_fetch_add(p, 1, __ATOMIC_RELAXED, __HIP_MEMORY_SCOPE_AGENT);
}
__device__ __forceinline__ void wait_ge(int* p, int tgt) {
    int guard = 0;
    while (rload(p) < tgt) { if (++guard > POLL_CAP) break; }
    __atomic_signal_fence(__ATOMIC_ACQUIRE);
}

// Device-scope (sc1) ring ops: coherent across XCDs at the MALL, MALL-cached.
__device__ __forceinline__ void stu_nw(uint* p, uint v) {     // fire-and-forget
    asm volatile("global_store_dword %0, %1, off sc1" :: "v"(p), "v"(v) : "memory");
}
__device__ __forceinline__ void st2_nw(uint* p, u32x2 v) {    // paired store
    asm volatile("global_store_dwordx2 %0, %1, off sc1" :: "v"(p), "v"(v) : "memory");
}

// Poll one 16B chunk until every 32-bit word's LSB == want.
__device__ __forceinline__ void poll1(const uint* p, uint want, u32x4& A) {
    int guard = 0;
    while (true) {
        u32x4 a;
        asm volatile("global_load_dwordx4 %0, %1, off sc1\n\ts_waitcnt vmcnt(0)"
                     : "=&v"(a) : "v"(p) : "memory");
        uint m = a[0] & a[1] & a[2] & a[3];
        uint o = a[0] | a[1] | a[2] | a[3];
        bool ok = want ? ((m & 1u) != 0u) : ((o & 1u) == 0u);
        if (ok || ++guard > POLL_CAP) { A = a; return; }
    }
}

__device__ __forceinline__ uint bf16hi(uint u) { return (u + 0x7FFFu + ((u >> 16) & 1u)) >> 16; }
__device__ __forceinline__ uint2 splitbf(float v) {
    uint uh = bf16hi(__float_as_uint(v));
    float rl = v - __uint_as_float(uh << 16);
    uint ul = bf16hi(__float_as_uint(rl));
    return make_uint2(uh, ul);
}

// ---------------------------------------------------------------------------
// Prep: wipe rings to tag=1 (0x00000001); zero counters; build A-fragments
// (split-bf16, MFMA lane order).
// ---------------------------------------------------------------------------
__global__ void lstm_prep(const float* __restrict__ w_is,
                          const float* __restrict__ w_ss,
                          float* __restrict__ ws, long long n_ws)
{
    const long long stride = (long long)gridDim.x * blockDim.x;
    const long long t0 = (long long)blockIdx.x * blockDim.x + threadIdx.x;
    uint* wsu = (uint*)ws;

    for (long long i = t0; i < 524288LL + 32768LL; i += stride) {
        long long a = (i < 524288LL) ? i : (CBX + (i - 524288LL));
        stu_nw(wsu + a, 0x00000001u);
    }
    for (long long i = CNT + t0; i < CNT + 4096; i += stride)
        stu_nw(wsu + i, 0u);

    if (n_ws >= WS_MIN) {
        ushort* af = (ushort*)(ws + AFB);
        for (long long e = t0; e < AF_N; e += stride) {
            int idx   = (int)e;
            int chunk = idx >> 9;           // (g*NRT+rt)*NKT + kt
            int lane  = (idx >> 3) & 63;
            int jj    = idx & 7;
            int g  = chunk / (10 * NKT);
            int rm = chunk % (10 * NKT);
            int rt = rm / NKT, kt = rm % NKT;
            int m = lane & 15, quad = lane >> 4;
            int r = rt * 16 + m;
            int q = r >> 5, hl = r & 31;
            int o = q * HD_ + g * GH + hl;
            int k = kt * 32 + quad * 8 + jj;
            float v;
            if (k < C_)            v = w_is[o * C_ + k];
            else if (k < C_ + HD_) v = w_ss[(o * HD_ + (k - C_)) * 2 + 1];
            else                   v = w_ss[(o * HD_ + (k - C_ - HD_)) * 2 + 0];
            uint uh = bf16hi(__float_as_uint(v));
            float rl = v - __uint_as_float(uh << 16);
            uint ul = bf16hi(__float_as_uint(rl));
            int base = chunk * 1024 + lane * 16 + jj;   // ushort units
            af[base]     = (ushort)uh;
            af[base + 8] = (ushort)ul;
        }
    }
}

// ---------------------------------------------------------------------------
// Coalesced transpose: x[b][c][hr][w] -> xT[b][hr][w][c] via 64x64 LDS tile.
// ---------------------------------------------------------------------------
__global__ void lstm_xpose(const float* __restrict__ x, float* __restrict__ ws)
{
    __shared__ float L[64 * 65];
    const int b = blockIdx.x >> 6, hr = blockIdx.x & 63;
    const int tid = threadIdx.x;          // 256 threads
    #pragma unroll
    for (int it = 0; it < 16; ++it) {
        int c = it * 4 + (tid >> 6), w = tid & 63;
        L[c * 65 + w] = x[(((size_t)b * C_ + c) * H_ + hr) * W_ + w];
    }
    __syncthreads();
    float* xt = ws + XT;
    #pragma unroll
    for (int it = 0; it < 16; ++it) {
        int w = it * 4 + (tid >> 6), c = tid & 63;
        xt[(((size_t)b * H_ + hr) * W_ + w) * C_ + c] = L[c * 65 + w];
    }
}

// ---------------------------------------------------------------------------
// Persistent kernel: 127 diagonal steps, self-tagged dataflow with
// DEDUPLICATED polls: 544 threads each poll one distinct dwordx4 of the
// 17-col x 128-hd window and write the 4 values into BOTH the unshifted
// (kt 2-5) and shifted (kt 6-9) B-fragments. 128 threads build x fragments
// (kt 0-1); c-poll/WAR on the 11th wave. 2 barriers/step; GEMM on waves 0-9
// with 2 acc chains. (Round-6 topology, proven 437us; only scope flag changed.)
// ---------------------------------------------------------------------------
__global__ void __launch_bounds__(NT, 2) lstm_persist(
    const float* __restrict__ x,
    const float* __restrict__ ws_c,
    const float* __restrict__ b_is,
    const float* __restrict__ b_ss,
    float* __restrict__ out,
    float* __restrict__ ws,
    int use_xt)
{
    __shared__ uint  Bf[NKT * 576];     // B-fragments: per kt, 64 lanes x (16B hi + 16B lo)
    __shared__ float Gp[ROWS * GPS];    // gate panel
    __shared__ float Cs[2][17 * GH];    // double-buffered c panel [colp][hl]
    __shared__ float bias_s[ROWS];

    const int tid = threadIdx.x;
    const int cgp = blockIdx.x >> 2;
    const int g   = blockIdx.x & 3;
    const int n0  = cgp * TC;
    const int inb  = (n0 & 63) != 0;
    const int hasr = ((n0 + TC) & 63) != 0;

    uint* hring = (uint*)ws;
    uint* cring = (uint*)(ws + CBX);
    int*  gcntp = (int*)(ws + GCNT);
    const float* xt = ws_c + XT;
    const uint4* afq = (const uint4*)(ws_c + AFB);

    if (tid < ROWS) {
        int q = tid >> 5, hl = tid & 31;
        int o = q * HD_ + g * GH + hl;
        bias_s[tid] = b_is[o] + b_ss[o];
    }
    if (tid < 17 * GH) Cs[0][tid] = 0.f;    // step-0 c panel
    if (tid >= 544 && tid < 544 + GH) Cs[1][tid - 544] = 0.f;   // boundary col, buf 1

    const int lane = tid & 63;
    const int wv   = tid >> 6;          // waves 0-9 = GEMM row-tiles
    const int quad = lane >> 4;
    const int colc = lane & 15;
    uint* bfr = &Bf[lane * 8 + ((lane >> 2) << 2)];   // GEMM read base

    // ---- poll-thread constants (tid < 544): one dwordx4 of the h window ----
    const int cp  = tid >> 5;           // window col 0..16 (global col n0-1+cp)
    const int ch  = tid & 31;           // hd chunk: hd = ch*4
    const int pq  = (ch >> 1) & 3;      // quad of the fragment lane
    const int pj0 = (ch & 1) * 4;       // jj offset (0 or 4)
    const int kta = 2 + (ch >> 3);      // unshifted k-tile (cols n0..n0+15)
    const int laneA = pq * 16 + ((cp >= 1) ? (cp - 1) : 0);
    const int laneB = pq * 16 + ((cp <= 15) ? cp : 0);
    uint* bfA = &Bf[laneA * 8 + ((laneA >> 2) << 2) + kta * 576 + (pj0 >> 1)];
    uint* bfB = &Bf[laneB * 8 + ((laneB >> 2) << 2) + (kta + 4) * 576 + (pj0 >> 1)];
    const uint* hbase = hring + (size_t)(n0 - 1 + cp) * 128 + ch * 4;
    const int pskip = (cp == 0 && !inb);

    // ---- x-thread constants (544 <= tid < 672): one lane of kt 0/1 ----
    const int xi = tid - 544;
    const int xkt = xi >> 6, xl = xi & 63;
    const int xq = xl >> 4, xcolc = xl & 15;
    const int xc0 = xkt * 32 + xq * 8;
    const int xn = n0 + xcolc, xb = xn >> 6, xhr = xn & 63;
    uint* bfX = &Bf[xl * 8 + ((xl >> 2) << 2) + xkt * 576];

    const int ci = tid - 672;           // 0..7: c-boundary poll; ==8: WAR wait

    // ---- A hi AND lo fragments pinned in registers (GEMM waves only) ----
    bf16x8 Ahr[NKT], Alr[NKT];
    if (wv < 10) {
        const uint4* ap0 = afq + (size_t)((g * 10 + wv) * NKT) * 128 + lane * 2;
        #pragma unroll
        for (int kt = 0; kt < NKT; ++kt) {
            uint4 ha = ap0[kt * 128];
            Ahr[kt] = *(bf16x8*)&ha;
            asm volatile("" : "+v"(Ahr[kt]));
            uint4 la = ap0[kt * 128 + 1];
            Alr[kt] = *(bf16x8*)&la;
            asm volatile("" : "+v"(Alr[kt]));
        }
    }

    __syncthreads();

    for (int j = 0; j < SW_; ++j) {
        const uint want = ((j - 1) >> 2) & 1u;   // expected tag of step j-1 data
        const uint wtag = (j >> 2) & 1u;         // tag we write at step j

        // ---- P1: build all B-fragments (dedup polls) + boundary work ----
        if (tid < 544) {
            u32x4 a = {0, 0, 0, 0};
            if (j > 0 && !pskip)
                poll1(hbase + (size_t)((j - 1) & 3) * HSLOT, want, a);
            uint2 e0 = splitbf(__uint_as_float(a[0]));
            uint2 e1 = splitbf(__uint_as_float(a[1]));
            uint2 e2 = splitbf(__uint_as_float(a[2]));
            uint2 e3 = splitbf(__uint_as_float(a[3]));
            u32x2 hp = {e0.x | (e1.x << 16), e2.x | (e3.x << 16)};
            u32x2 lp = {e0.y | (e1.y << 16), e2.y | (e3.y << 16)};
            if (cp >= 1)  { *(u32x2*)bfA = hp; *(u32x2*)(bfA + 4) = lp; }
            if (cp <= 15) { *(u32x2*)bfB = hp; *(u32x2*)(bfB + 4) = lp; }
        } else if (tid < 672) {
            float xv[8];
            int w = j - xhr;
            if ((unsigned)w < (unsigned)W_) {
                if (use_xt) {
                    const float* xp = xt + (((size_t)xb * H_ + xhr) * W_ + w) * C_ + xc0;
                    f32x4 va = *(const f32x4*)xp, vb = *(const f32x4*)(xp + 4);
                    #pragma unroll
                    for (int r = 0; r < 4; ++r) { xv[r] = va[r]; xv[4 + r] = vb[r]; }
                } else {
                    #pragma unroll
                    for (int r = 0; r < 8; ++r)
                        xv[r] = x[(((size_t)xb * C_ + xc0 + r) * H_ + xhr) * W_ + w];
                }
            } else {
                #pragma unroll
                for (int r = 0; r < 8; ++r) xv[r] = 0.f;
            }
            uint hw[4], lw[4];
            #pragma unroll
            for (int p = 0; p < 4; ++p) {
                uint2 e0 = splitbf(xv[2 * p]), e1 = splitbf(xv[2 * p + 1]);
                hw[p] = e0.x | (e1.x << 16);
                lw[p] = e0.y | (e1.y << 16);
            }
            *(uint4*)bfX       = make_uint4(hw[0], hw[1], hw[2], hw[3]);
            *(uint4*)(bfX + 4) = make_uint4(lw[0], lw[1], lw[2], lw[3]);
        } else if (ci >= 0 && ci < 8) {              // c-boundary poll (32 floats)
            if (inb && j > 0) {
                u32x4 cv;
                const uint* cpx = cring +
                    (((size_t)((j - 1) & 3) * NCG + (cgp - 1)) * NG + g) * GH + ci * 4;
                poll1(cpx, want, cv);
                #pragma unroll
                for (int r = 0; r < 4; ++r)
                    Cs[j & 1][ci * 4 + r] = __uint_as_float(cv[r]);
            }
        } else if (ci == 8) {                        // WAR: right cluster read j-3
            if (j >= 4 && hasr) wait_ge(gcntp + (cgp + 1) * 32, 4 * (j - 2));
        }
        __syncthreads();                             // sync_a: Bf/Cs ready
        if (tid == 0) rbump(gcntp + cgp * 32);       // our step-(j-1) reads done

        // ---- GEMM: rows [wv*16,+16) x 16 cols, K=320, 2 acc chains ----
        if (wv < 10) {
            f32x4 acc0 = {0.f, 0.f, 0.f, 0.f};
            f32x4 acc1 = {0.f, 0.f, 0.f, 0.f};
            __builtin_amdgcn_s_setprio(1);
            #pragma unroll
            for (int kt = 0; kt < NKT; kt += 2) {
                const uint* bp0 = bfr + kt * 576;
                uint4 hb0 = *(const uint4*)bp0;
                uint4 lb0 = *(const uint4*)(bp0 + 4);
                const uint* bp1 = bfr + (kt + 1) * 576;
                uint4 hb1 = *(const uint4*)bp1;
                uint4 lb1 = *(const uint4*)(bp1 + 4);
                bf16x8 Bh0 = *(bf16x8*)&hb0, Bl0 = *(bf16x8*)&lb0;
                bf16x8 Bh1 = *(bf16x8*)&hb1, Bl1 = *(bf16x8*)&lb1;
                acc0 = __builtin_amdgcn_mfma_f32_16x16x32_bf16(Ahr[kt],     Bh0, acc0, 0, 0, 0);
                acc1 = __builtin_amdgcn_mfma_f32_16x16x32_bf16(Ahr[kt + 1], Bh1, acc1, 0, 0, 0);
                acc0 = __builtin_amdgcn_mfma_f32_16x16x32_bf16(Ahr[kt],     Bl0, acc0, 0, 0, 0);
                acc1 = __builtin_amdgcn_mfma_f32_16x16x32_bf16(Ahr[kt + 1], Bl1, acc1, 0, 0, 0);
                acc0 = __builtin_amdgcn_mfma_f32_16x16x32_bf16(Alr[kt],     Bh0, acc0, 0, 0, 0);
                acc1 = __builtin_amdgcn_mfma_f32_16x16x32_bf16(Alr[kt + 1], Bh1, acc1, 0, 0, 0);
                acc0 = __builtin_amdgcn_mfma_f32_16x16x32_bf16(Alr[kt],     Bl0, acc0, 0, 0, 0);
                acc1 = __builtin_amdgcn_mfma_f32_16x16x32_bf16(Alr[kt + 1], Bl1, acc1, 0, 0, 0);
            }
            __builtin_amdgcn_s_setprio(0);
            #pragma unroll
            for (int r = 0; r < 4; ++r)
                Gp[(wv * 16 + quad * 4 + r) * GPS + colc] = acc0[r] + acc1[r];
        }
        __syncthreads();                             // sync_b: gates ready

        // ---- nonlin + state update + tagged ring stores (fire-and-forget) ----
        if (tid < GH * TC) {
            const int hl = tid & 31, col = tid >> 5;
            int n = n0 + col, b = n >> 6, hr = n & 63;
            float go  = Gp[(0 * GH + hl) * GPS + col] + bias_s[0 * GH + hl];
            float gfl = Gp[(1 * GH + hl) * GPS + col] + bias_s[1 * GH + hl];
            float gfu = Gp[(2 * GH + hl) * GPS + col] + bias_s[2 * GH + hl];
            float gi  = Gp[(3 * GH + hl) * GPS + col] + bias_s[3 * GH + hl];
            float gg  = Gp[(4 * GH + hl) * GPS + col] + bias_s[4 * GH + hl];
            float so = sigm(go), sfl = sigm(gfl), sfu = sigm(gfu), si = sigm(gi);
            float tg = tanh_fast(gg);
            float cp_ = Cs[j & 1][(col + 1) * GH + hl];
            float cs = Cs[j & 1][col * GH + hl];
            float cv = sfl * cp_ + sfu * cs + si * tg;
            float hv = so * tanh_fast(cv);
            Cs[(j + 1) & 1][(col + 1) * GH + hl] = cv;   // disjoint from boundary [0,32)

            uint pk = (__float_as_uint(hv) & ~1u) | wtag;   // tag in fp32 LSB: 2^-24
            uint other = (uint)__shfl_xor((int)pk, 1);
            if (!(hl & 1)) {                                // paired store: 2 hd per req
                u32x2 pv = {pk, other};
                st2_nw(hring + (size_t)(j & 3) * HSLOT + (size_t)n * 128 + g * GH + (hl & ~1), pv);
            }
            if (col == TC - 1) {
                uint cpk = (__float_as_uint(cv) & ~1u) | wtag;
                stu_nw(cring + (((size_t)(j & 3) * NCG + cgp) * NG + g) * GH + hl, cpk);
            }
            int w = j - hr;
            if ((unsigned)w < (unsigned)W_)
                out[(((size_t)b * HD_ + g * GH + hl) * H_ + hr) * W_ + w] = hv;
        }
        // no third barrier: Bf rewrite (next P1) is fenced by sync_b (GEMM reads
        // done); Gp rewrite fenced by next sync_a; Cs buffers alternate.
    }
}

// ---------------------------------------------------------------------------
extern "C" void kernel_launch(void* const* d_in, const int* in_sizes, int n_in,
                              void* d_out, int out_size, void* d_ws, size_t ws_size,
                              hipStream_t stream)
{
    const float* x    = (const float*)d_in[0];
    const float* w_is = (const float*)d_in[1];
    const float* b_is = (const float*)d_in[2];
    const float* w_ss = (const float*)d_in[3];
    const float* b_ss = (const float*)d_in[4];
    float* out = (float*)d_out;
    float* ws  = (float*)d_ws;

    const long long n_ws = (long long)(ws_size / 4);
    const int use_xt = (n_ws >= WS_XT) ? 1 : 0;

    hipLaunchKernelGGL(lstm_prep, dim3(1024), dim3(256), 0, stream,
                       w_is, w_ss, ws, n_ws);
    if (use_xt)
        hipLaunchKernelGGL(lstm_xpose, dim3(B_ * H_), dim3(256), 0, stream, x, ws);

    hipLaunchKernelGGL(lstm_persist, dim3(NG * NCG), dim3(NT), 0, stream,
                       x, ws, b_is, b_ss, out, ws, use_xt);
}

// Round 10
// 483.367 us; speedup vs baseline: 1.3100x; 1.0187x over previous
//
#include <hip/hip_runtime.h>

typedef __attribute__((ext_vector_type(8))) short bf16x8;
typedef __attribute__((ext_vector_type(4))) float f32x4;
typedef __attribute__((ext_vector_type(4))) uint  u32x4;
typedef __attribute__((ext_vector_type(2))) uint  u32x2;

// Problem constants
#define B_   16
#define C_   64
#define H_   64
#define W_   64
#define HD_  128
#define K_   320      // C + 2*HD
#define SW_  127      // H+W-1

// Decomposition: 4 hd-groups (32 hd each) x 64 col-clusters (16 cols each) = 256 blocks
#define NG    4
#define GH    32      // hd per group
#define NCG   64      // clusters
#define TC    16      // cols per cluster
#define NT    704     // threads per block (11 waves: 10 GEMM + 1 aux)
#define ROWS  160     // gate rows per block (5 gates x 32 hd)
#define NKT   10      // K/32 k-tiles
#define GPS   17      // gate-panel stride

// Workspace layout (float/uint offsets).
// MALL h ring (sc1): 4 slots x 1024 cols x 128 hd, fp32 + pass-parity tag in
// mantissa LSB (2^-24, numerically free). Per-word tags: data is its own
// flag, RAW chain = store -> poll-hit. (Round-9's XCD-local L2 ring was
// UNSOUND: tag parity has period 8, so lines stale by exactly 8 steps pass
// the check — cross-XCD plain-store exchange can silently alias. Reverted.)
// OSC: out-staging [n][w][hd] — per-step stores become 128B-contiguous
// cache-line writes (direct out stores were 4KB-strided 4B -> ~16x DRAM
// sector amplification, 403MB WRITE_SIZE), transposed to out by a post-pass.
#define HSLOT  131072LL
#define CBX    524288LL                    // c boundary ring: 4 x NCG x NG x GH
#define CNT    557056LL                    // (legacy region, zeroed)
#define GCNT   559104LL                    // 64 WAR tokens, stride 32 ints
#define AFB    561152LL                    // A-fragments: 204800 floats (hi+lo bf16)
#define AF_N   204800LL
#define XT     765952LL                    // xT[b][hr][w][c]
#define XT_N   4194304LL
#define OSC    (XT + XT_N)                 // out staging: 1024 x 64 x 128
#define OSC_N  8388608LL
#define WS_MIN (AFB + AF_N)
#define WS_XT  (XT + XT_N)
#define WS_OSC (OSC + OSC_N)

#define POLL_CAP (1 << 20)   // safety: a protocol bug fails absmax instead of hanging

__device__ __forceinline__ float sigm(float v) { return 1.f / (1.f + __expf(-v)); }
__device__ __forceinline__ float tanh_fast(float v) {
    float e = __expf(2.f * v);
    return 1.f - 2.f / (e + 1.f);
}

__device__ __forceinline__ int rload(int* p) {
    return __hip_atomic_load(p, __ATOMIC_RELAXED, __HIP_MEMORY_SCOPE_AGENT);
}
__device__ __forceinline__ void rbump(int* p) {
    __hip_atomic_fetch_add(p, 1, __ATOMIC_RELAXED, __HIP_MEMORY_SCOPE_AGENT);
}
__device__ __forceinline__ void wait_ge(int* p, int tgt) {
    int guard = 0;
    while (rload(p) < tgt) { if (++guard > POLL_CAP) break; }
    __atomic_signal_fence(__ATOMIC_ACQUIRE);
}

// Device-scope (sc1) ring ops: coherent across XCDs at the MALL.
__device__ __forceinline__ void stu_nw(uint* p, uint v) {     // fire-and-forget
    asm volatile("global_store_dword %0, %1, off sc1" :: "v"(p), "v"(v) : "memory");
}
__device__ __forceinline__ void st2_nw(uint* p, u32x2 v) {    // paired store
    asm volatile("global_store_dwordx2 %0, %1, off sc1" :: "v"(p), "v"(v) : "memory");
}

// Poll one 16B chunk (sc1 / MALL) until every word's LSB == want.
__device__ __forceinline__ void poll1(const uint* p, uint want, u32x4& A) {
    int guard = 0;
    while (true) {
        u32x4 a;
        asm volatile("global_load_dwordx4 %0, %1, off sc1\n\ts_waitcnt vmcnt(0)"
                     : "=&v"(a) : "v"(p) : "memory");
        uint m = a[0] & a[1] & a[2] & a[3];
        uint o = a[0] | a[1] | a[2] | a[3];
        bool ok = want ? ((m & 1u) != 0u) : ((o & 1u) == 0u);
        if (ok || ++guard > POLL_CAP) { A = a; return; }
    }
}

__device__ __forceinline__ uint bf16hi(uint u) { return (u + 0x7FFFu + ((u >> 16) & 1u)) >> 16; }
__device__ __forceinline__ uint2 splitbf(float v) {
    uint uh = bf16hi(__float_as_uint(v));
    float rl = v - __uint_as_float(uh << 16);
    uint ul = bf16hi(__float_as_uint(rl));
    return make_uint2(uh, ul);
}

// ---------------------------------------------------------------------------
// Prep (merged): wipe MALL rings to tag=1; zero counters; build A-fragments;
// blocks >= 1024 additionally transpose x -> xT (64x64 LDS tile, coalesced).
// ---------------------------------------------------------------------------
__global__ void lstm_prep(const float* __restrict__ x,
                          const float* __restrict__ w_is,
                          const float* __restrict__ w_ss,
                          float* __restrict__ ws, long long n_ws, int use_xt)
{
    __shared__ float L[64 * 65];
    const long long stride = (long long)gridDim.x * blockDim.x;
    const long long t0 = (long long)blockIdx.x * blockDim.x + threadIdx.x;
    uint* wsu = (uint*)ws;

    for (long long i = t0; i < 524288LL + 32768LL; i += stride) {
        long long a = (i < 524288LL) ? i : (CBX + (i - 524288LL));
        stu_nw(wsu + a, 0x00000001u);
    }
    for (long long i = CNT + t0; i < CNT + 4096; i += stride)
        stu_nw(wsu + i, 0u);

    if (n_ws >= WS_MIN) {
        ushort* af = (ushort*)(ws + AFB);
        for (long long e = t0; e < AF_N; e += stride) {
            int idx   = (int)e;
            int chunk = idx >> 9;           // (g*NRT+rt)*NKT + kt
            int lane  = (idx >> 3) & 63;
            int jj    = idx & 7;
            int g  = chunk / (10 * NKT);
            int rm = chunk % (10 * NKT);
            int rt = rm / NKT, kt = rm % NKT;
            int m = lane & 15, quad = lane >> 4;
            int r = rt * 16 + m;
            int q = r >> 5, hl = r & 31;
            int o = q * HD_ + g * GH + hl;
            int k = kt * 32 + quad * 8 + jj;
            float v;
            if (k < C_)            v = w_is[o * C_ + k];
            else if (k < C_ + HD_) v = w_ss[(o * HD_ + (k - C_)) * 2 + 1];
            else                   v = w_ss[(o * HD_ + (k - C_ - HD_)) * 2 + 0];
            uint uh = bf16hi(__float_as_uint(v));
            float rl = v - __uint_as_float(uh << 16);
            uint ul = bf16hi(__float_as_uint(rl));
            int base = chunk * 1024 + lane * 16 + jj;   // ushort units
            af[base]     = (ushort)uh;
            af[base + 8] = (ushort)ul;
        }
    }

    if (use_xt && blockIdx.x >= 1024) {
        const int bb = blockIdx.x - 1024;
        const int b = bb >> 6, hr = bb & 63;
        const int tid = threadIdx.x;          // 256 threads
        #pragma unroll
        for (int it = 0; it < 16; ++it) {
            int c = it * 4 + (tid >> 6), w = tid & 63;
            L[c * 65 + w] = x[(((size_t)b * C_ + c) * H_ + hr) * W_ + w];
        }
        __syncthreads();
        float* xt = ws + XT;
        #pragma unroll
        for (int it = 0; it < 16; ++it) {
            int w = it * 4 + (tid >> 6), c = tid & 63;
            xt[(((size_t)b * H_ + hr) * W_ + w) * C_ + c] = L[c * 65 + w];
        }
    }
}

// ---------------------------------------------------------------------------
// Post-pass: osc[n][w][hd] -> out[b][hd][hr][w], both sides coalesced.
// ---------------------------------------------------------------------------
__global__ void lstm_oxpose(const float* __restrict__ ws, float* __restrict__ out)
{
    __shared__ float L[64 * 129];
    const int n = blockIdx.x, b = n >> 6, hr = n & 63;
    const float* osc = ws + OSC + (size_t)n * 64 * 128;
    const int tid = threadIdx.x;          // 256 threads
    #pragma unroll
    for (int it = 0; it < 32; ++it) {
        int e = it * 256 + tid;
        int w = e >> 7, hd = e & 127;
        L[w * 129 + hd] = osc[e];
    }
    __syncthreads();
    #pragma unroll
    for (int it = 0; it < 32; ++it) {
        int e = it * 256 + tid;
        int hd = e >> 6, w = e & 63;
        out[(((size_t)b * HD_ + hd) * H_ + hr) * W_ + w] = L[w * 129 + hd];
    }
}

// ---------------------------------------------------------------------------
// Persistent kernel: 127 diagonal steps, self-tagged dataflow with
// DEDUPLICATED polls: 544 threads each poll one distinct dwordx4 of the
// 17-col x 128-hd window and write the 4 values into BOTH the unshifted
// (kt 2-5) and shifted (kt 6-9) B-fragments. 128 threads build x fragments
// (kt 0-1); c-poll/WAR on the 11th wave. 2 barriers/step; GEMM on waves 0-9
// with 2 acc chains. (Round-8 topology, proven 434us; out staged to osc.)
// ---------------------------------------------------------------------------
__global__ void __launch_bounds__(NT, 2) lstm_persist(
    const float* __restrict__ x,
    const float* __restrict__ ws_c,
    const float* __restrict__ b_is,
    const float* __restrict__ b_ss,
    float* __restrict__ out,
    float* __restrict__ ws,
    int use_xt, int use_osc)
{
    __shared__ uint  Bf[NKT * 576];     // B-fragments: per kt, 64 lanes x (16B hi + 16B lo)
    __shared__ float Gp[ROWS * GPS];    // gate panel
    __shared__ float Cs[2][17 * GH];    // double-buffered c panel [colp][hl]
    __shared__ float bias_s[ROWS];

    const int tid = threadIdx.x;
    const int cgp = blockIdx.x >> 2;
    const int g   = blockIdx.x & 3;
    const int n0  = cgp * TC;
    const int inb  = (n0 & 63) != 0;
    const int hasr = ((n0 + TC) & 63) != 0;

    uint* hring = (uint*)ws;
    uint* cring = (uint*)(ws + CBX);
    int*  gcntp = (int*)(ws + GCNT);
    float* osc = ws + OSC;
    const float* xt = ws_c + XT;
    const uint4* afq = (const uint4*)(ws_c + AFB);

    if (tid < ROWS) {
        int q = tid >> 5, hl = tid & 31;
        int o = q * HD_ + g * GH + hl;
        bias_s[tid] = b_is[o] + b_ss[o];
    }
    if (tid < 17 * GH) Cs[0][tid] = 0.f;    // step-0 c panel
    if (tid >= 544 && tid < 544 + GH) Cs[1][tid - 544] = 0.f;   // boundary col, buf 1

    const int lane = tid & 63;
    const int wv   = tid >> 6;          // waves 0-9 = GEMM row-tiles
    const int quad = lane >> 4;
    const int colc = lane & 15;
    uint* bfr = &Bf[lane * 8 + ((lane >> 2) << 2)];   // GEMM read base

    // ---- poll-thread constants (tid < 544): one dwordx4 of the h window ----
    const int cp  = tid >> 5;           // window col 0..16 (global col n0-1+cp)
    const int ch  = tid & 31;           // hd chunk: hd = ch*4
    const int pq  = (ch >> 1) & 3;      // quad of the fragment lane
    const int pj0 = (ch & 1) * 4;       // jj offset (0 or 4)
    const int kta = 2 + (ch >> 3);      // unshifted k-tile (cols n0..n0+15)
    const int laneA = pq * 16 + ((cp >= 1) ? (cp - 1) : 0);
    const int laneB = pq * 16 + ((cp <= 15) ? cp : 0);
    uint* bfA = &Bf[laneA * 8 + ((laneA >> 2) << 2) + kta * 576 + (pj0 >> 1)];
    uint* bfB = &Bf[laneB * 8 + ((laneB >> 2) << 2) + (kta + 4) * 576 + (pj0 >> 1)];
    const uint* hbase = hring + (size_t)(n0 - 1 + cp) * 128 + ch * 4;
    const int pskip = (cp == 0 && !inb);

    // ---- x-thread constants (544 <= tid < 672): one lane of kt 0/1 ----
    const int xi = tid - 544;
    const int xkt = xi >> 6, xl = xi & 63;
    const int xq = xl >> 4, xcolc = xl & 15;
    const int xc0 = xkt * 32 + xq * 8;
    const int xn = n0 + xcolc, xb = xn >> 6, xhr = xn & 63;
    uint* bfX = &Bf[xl * 8 + ((xl >> 2) << 2) + xkt * 576];

    const int ci = tid - 672;           // 0..7: c-boundary poll; ==8: WAR wait

    // ---- A hi AND lo fragments pinned in registers (GEMM waves only) ----
    bf16x8 Ahr[NKT], Alr[NKT];
    if (wv < 10) {
        const uint4* ap0 = afq + (size_t)((g * 10 + wv) * NKT) * 128 + lane * 2;
        #pragma unroll
        for (int kt = 0; kt < NKT; ++kt) {
            uint4 ha = ap0[kt * 128];
            Ahr[kt] = *(bf16x8*)&ha;
            asm volatile("" : "+v"(Ahr[kt]));
            uint4 la = ap0[kt * 128 + 1];
            Alr[kt] = *(bf16x8*)&la;
            asm volatile("" : "+v"(Alr[kt]));
        }
    }

    __syncthreads();

    for (int j = 0; j < SW_; ++j) {
        const uint want = ((j - 1) >> 2) & 1u;   // expected tag of step j-1 data
        const uint wtag = (j >> 2) & 1u;         // tag we write at step j

        // ---- P1: build all B-fragments (dedup polls) + boundary work ----
        if (tid < 544) {
            u32x4 a = {0, 0, 0, 0};
            if (j > 0 && !pskip)
                poll1(hbase + (size_t)((j - 1) & 3) * HSLOT, want, a);
            uint2 e0 = splitbf(__uint_as_float(a[0]));
            uint2 e1 = splitbf(__uint_as_float(a[1]));
            uint2 e2 = splitbf(__uint_as_float(a[2]));
            uint2 e3 = splitbf(__uint_as_float(a[3]));
            u32x2 hp = {e0.x | (e1.x << 16), e2.x | (e3.x << 16)};
            u32x2 lp = {e0.y | (e1.y << 16), e2.y | (e3.y << 16)};
            if (cp >= 1)  { *(u32x2*)bfA = hp; *(u32x2*)(bfA + 4) = lp; }
            if (cp <= 15) { *(u32x2*)bfB = hp; *(u32x2*)(bfB + 4) = lp; }
        } else if (tid < 672) {
            float xv[8];
            int w = j - xhr;
            if ((unsigned)w < (unsigned)W_) {
                if (use_xt) {
                    const float* xp = xt + (((size_t)xb * H_ + xhr) * W_ + w) * C_ + xc0;
                    f32x4 va = *(const f32x4*)xp, vb = *(const f32x4*)(xp + 4);
                    #pragma unroll
                    for (int r = 0; r < 4; ++r) { xv[r] = va[r]; xv[4 + r] = vb[r]; }
                } else {
                    #pragma unroll
                    for (int r = 0; r < 8; ++r)
                        xv[r] = x[(((size_t)xb * C_ + xc0 + r) * H_ + xhr) * W_ + w];
                }
            } else {
                #pragma unroll
                for (int r = 0; r < 8; ++r) xv[r] = 0.f;
            }
            uint hw[4], lw[4];
            #pragma unroll
            for (int p = 0; p < 4; ++p) {
                uint2 e0 = splitbf(xv[2 * p]), e1 = splitbf(xv[2 * p + 1]);
                hw[p] = e0.x | (e1.x << 16);
                lw[p] = e0.y | (e1.y << 16);
            }
            *(uint4*)bfX       = make_uint4(hw[0], hw[1], hw[2], hw[3]);
            *(uint4*)(bfX + 4) = make_uint4(lw[0], lw[1], lw[2], lw[3]);
        } else if (ci >= 0 && ci < 8) {              // c-boundary poll (32 floats)
            if (inb && j > 0) {
                u32x4 cv;
                const uint* cpx = cring +
                    (((size_t)((j - 1) & 3) * NCG + (cgp - 1)) * NG + g) * GH + ci * 4;
                poll1(cpx, want, cv);
                #pragma unroll
                for (int r = 0; r < 4; ++r)
                    Cs[j & 1][ci * 4 + r] = __uint_as_float(cv[r]);
            }
        } else if (ci == 8) {                        // WAR: right cluster read j-3
            if (j >= 4 && hasr) wait_ge(gcntp + (cgp + 1) * 32, 4 * (j - 2));
        }
        __syncthreads();                             // sync_a: Bf/Cs ready
        if (tid == 0) rbump(gcntp + cgp * 32);       // our step-(j-1) reads done

        // ---- GEMM: rows [wv*16,+16) x 16 cols, K=320, 2 acc chains ----
        if (wv < 10) {
            f32x4 acc0 = {0.f, 0.f, 0.f, 0.f};
            f32x4 acc1 = {0.f, 0.f, 0.f, 0.f};
            __builtin_amdgcn_s_setprio(1);
            #pragma unroll
            for (int kt = 0; kt < NKT; kt += 2) {
                const uint* bp0 = bfr + kt * 576;
                uint4 hb0 = *(const uint4*)bp0;
                uint4 lb0 = *(const uint4*)(bp0 + 4);
                const uint* bp1 = bfr + (kt + 1) * 576;
                uint4 hb1 = *(const uint4*)bp1;
                uint4 lb1 = *(const uint4*)(bp1 + 4);
                bf16x8 Bh0 = *(bf16x8*)&hb0, Bl0 = *(bf16x8*)&lb0;
                bf16x8 Bh1 = *(bf16x8*)&hb1, Bl1 = *(bf16x8*)&lb1;
                acc0 = __builtin_amdgcn_mfma_f32_16x16x32_bf16(Ahr[kt],     Bh0, acc0, 0, 0, 0);
                acc1 = __builtin_amdgcn_mfma_f32_16x16x32_bf16(Ahr[kt + 1], Bh1, acc1, 0, 0, 0);
                acc0 = __builtin_amdgcn_mfma_f32_16x16x32_bf16(Ahr[kt],     Bl0, acc0, 0, 0, 0);
                acc1 = __builtin_amdgcn_mfma_f32_16x16x32_bf16(Ahr[kt + 1], Bl1, acc1, 0, 0, 0);
                acc0 = __builtin_amdgcn_mfma_f32_16x16x32_bf16(Alr[kt],     Bh0, acc0, 0, 0, 0);
                acc1 = __builtin_amdgcn_mfma_f32_16x16x32_bf16(Alr[kt + 1], Bh1, acc1, 0, 0, 0);
                acc0 = __builtin_amdgcn_mfma_f32_16x16x32_bf16(Alr[kt],     Bl0, acc0, 0, 0, 0);
                acc1 = __builtin_amdgcn_mfma_f32_16x16x32_bf16(Alr[kt + 1], Bl1, acc1, 0, 0, 0);
            }
            __builtin_amdgcn_s_setprio(0);
            #pragma unroll
            for (int r = 0; r < 4; ++r)
                Gp[(wv * 16 + quad * 4 + r) * GPS + colc] = acc0[r] + acc1[r];
        }
        __syncthreads();                             // sync_b: gates ready

        // ---- nonlin + state update + tagged ring stores (fire-and-forget) ----
        if (tid < GH * TC) {
            const int hl = tid & 31, col = tid >> 5;
            int n = n0 + col, b = n >> 6, hr = n & 63;
            float go  = Gp[(0 * GH + hl) * GPS + col] + bias_s[0 * GH + hl];
            float gfl = Gp[(1 * GH + hl) * GPS + col] + bias_s[1 * GH + hl];
            float gfu = Gp[(2 * GH + hl) * GPS + col] + bias_s[2 * GH + hl];
            float gi  = Gp[(3 * GH + hl) * GPS + col] + bias_s[3 * GH + hl];
            float gg  = Gp[(4 * GH + hl) * GPS + col] + bias_s[4 * GH + hl];
            float so = sigm(go), sfl = sigm(gfl), sfu = sigm(gfu), si = sigm(gi);
            float tg = tanh_fast(gg);
            float cp_ = Cs[j & 1][(col + 1) * GH + hl];
            float cs = Cs[j & 1][col * GH + hl];
            float cv = sfl * cp_ + sfu * cs + si * tg;
            float hv = so * tanh_fast(cv);
            Cs[(j + 1) & 1][(col + 1) * GH + hl] = cv;   // disjoint from boundary [0,32)

            uint pk = (__float_as_uint(hv) & ~1u) | wtag;   // tag in fp32 LSB: 2^-24
            uint other = (uint)__shfl_xor((int)pk, 1);
            if (!(hl & 1)) {                                // paired store: 2 hd per req
                u32x2 pv = {pk, other};
                st2_nw(hring + (size_t)(j & 3) * HSLOT + (size_t)n * 128 + g * GH + (hl & ~1), pv);
            }
            if (col == TC - 1) {
                uint cpk = (__float_as_uint(cv) & ~1u) | wtag;
                stu_nw(cring + (((size_t)(j & 3) * NCG + cgp) * NG + g) * GH + hl, cpk);
            }
            int w = j - hr;
            if ((unsigned)w < (unsigned)W_) {
                if (use_osc)                                 // 128B-contiguous lines
                    osc[((size_t)n * 64 + w) * 128 + g * GH + hl] = hv;
                else
                    out[(((size_t)b * HD_ + g * GH + hl) * H_ + hr) * W_ + w] = hv;
            }
        }
        // no third barrier: Bf rewrite (next P1) is fenced by sync_b (GEMM reads
        // done); Gp rewrite fenced by next sync_a; Cs buffers alternate.
    }
}

// ---------------------------------------------------------------------------
extern "C" void kernel_launch(void* const* d_in, const int* in_sizes, int n_in,
                              void* d_out, int out_size, void* d_ws, size_t ws_size,
                              hipStream_t stream)
{
    const float* x    = (const float*)d_in[0];
    const float* w_is = (const float*)d_in[1];
    const float* b_is = (const float*)d_in[2];
    const float* w_ss = (const float*)d_in[3];
    const float* b_ss = (const float*)d_in[4];
    float* out = (float*)d_out;
    float* ws  = (float*)d_ws;

    const long long n_ws = (long long)(ws_size / 4);
    const int use_xt  = (n_ws >= WS_XT)  ? 1 : 0;
    const int use_osc = (n_ws >= WS_OSC) ? 1 : 0;

    hipLaunchKernelGGL(lstm_prep, dim3(2048), dim3(256), 0, stream,
                       x, w_is, w_ss, ws, n_ws, use_xt);

    hipLaunchKernelGGL(lstm_persist, dim3(NG * NCG), dim3(NT), 0, stream,
                       x, ws, b_is, b_ss, out, ws, use_xt, use_osc);

    if (use_osc)
        hipLaunchKernelGGL(lstm_oxpose, dim3(1024), dim3(256), 0, stream, ws, out);
}

// Round 13
// 464.064 us; speedup vs baseline: 1.3645x; 1.0416x over previous
//
#include <hip/hip_runtime.h>

typedef __attribute__((ext_vector_type(8))) short bf16x8;
typedef __attribute__((ext_vector_type(4))) float f32x4;
typedef __attribute__((ext_vector_type(4))) uint  u32x4;
typedef __attribute__((ext_vector_type(2))) uint  u32x2;

// Problem constants
#define B_   16
#define C_   64
#define H_   64
#define W_   64
#define HD_  128
#define K_   320      // C + 2*HD
#define SW_  127      // H+W-1

// Decomposition: 4 hd-groups (32 hd each) x 64 col-clusters (16 cols each) = 256 blocks
#define NG    4
#define GH    32      // hd per group
#define NCG   64      // clusters
#define TC    16      // cols per cluster
#define NT    704     // threads per block (11 waves: 10 GEMM + 1 aux)
#define ROWS  160     // gate rows per block (5 gates x 32 hd)
#define NKT   10      // K/32 k-tiles
#define GPS   17      // gate-panel stride

// Workspace layout (float/uint offsets).
// MALL h ring (sc1): 4 slots x 1024 cols x 128 hd, fp32 + pass-parity tag in
// mantissa LSB (2^-24, numerically free). Per-word tags: data is its own
// flag; RAW chain = store -> poll-hit. Own-slice fragments (ch>>3 == g,
// cp>=1) are built via wave-shuffle in the post phase (no MALL roundtrip,
// ~24% less poll traffic). POLL RULE (round-12 NaN lesson): the load and its
// s_waitcnt MUST live in ONE asm block — a split load/wait exposes in-flight
// destination registers to regalloc phi-copies, which read garbage.
#define HSLOT  131072LL
#define CBX    524288LL                    // c boundary ring: 4 x NCG x NG x GH
#define CNT    557056LL                    // (legacy region, zeroed)
#define GCNT   559104LL                    // 64 WAR tokens, stride 32 ints
#define AFB    561152LL                    // A-fragments: 204800 floats (hi+lo bf16)
#define AF_N   204800LL
#define XT     765952LL                    // xT[b][hr][w][c]
#define XT_N   4194304LL
#define OSC    (XT + XT_N)                 // out staging: 1024 x 64 x 128
#define OSC_N  8388608LL
#define WS_MIN (AFB + AF_N)
#define WS_XT  (XT + XT_N)
#define WS_OSC (OSC + OSC_N)

#define POLL_CAP (1 << 20)   // safety: a protocol bug fails absmax instead of hanging

__device__ __forceinline__ float sigm(float v) { return 1.f / (1.f + __expf(-v)); }
__device__ __forceinline__ float tanh_fast(float v) {
    float e = __expf(2.f * v);
    return 1.f - 2.f / (e + 1.f);
}

__device__ __forceinline__ int rload(int* p) {
    return __hip_atomic_load(p, __ATOMIC_RELAXED, __HIP_MEMORY_SCOPE_AGENT);
}
__device__ __forceinline__ void rbump(int* p) {
    __hip_atomic_fetch_add(p, 1, __ATOMIC_RELAXED, __HIP_MEMORY_SCOPE_AGENT);
}
__device__ __forceinline__ void wait_ge(int* p, int tgt) {
    int guard = 0;
    while (rload(p) < tgt) { if (++guard > POLL_CAP) break; }
    __atomic_signal_fence(__ATOMIC_ACQUIRE);
}

// Device-scope (sc1) ring ops: coherent across XCDs at the MALL.
__device__ __forceinline__ void stu_nw(uint* p, uint v) {     // fire-and-forget
    asm volatile("global_store_dword %0, %1, off sc1" :: "v"(p), "v"(v) : "memory");
}
__device__ __forceinline__ void st2_nw(uint* p, u32x2 v) {    // paired store
    asm volatile("global_store_dwordx2 %0, %1, off sc1" :: "v"(p), "v"(v) : "memory");
}

// Poll one 16B chunk until every word's LSB == want. Load + waitcnt in ONE
// asm block (atomic w.r.t. compiler scheduling/regalloc — see header note).
__device__ __forceinline__ void poll1(const uint* p, uint want, u32x4& A) {
    int guard = 0;
    while (true) {
        u32x4 a;
        asm volatile("global_load_dwordx4 %0, %1, off sc1\n\ts_waitcnt vmcnt(0)"
                     : "=&v"(a) : "v"(p) : "memory");
        uint m = a[0] & a[1] & a[2] & a[3];
        uint o = a[0] | a[1] | a[2] | a[3];
        bool ok = want ? ((m & 1u) != 0u) : ((o & 1u) == 0u);
        if (ok || ++guard > POLL_CAP) { A = a; return; }
    }
}

__device__ __forceinline__ uint bf16hi(uint u) { return (u + 0x7FFFu + ((u >> 16) & 1u)) >> 16; }
__device__ __forceinline__ uint2 splitbf(float v) {
    uint uh = bf16hi(__float_as_uint(v));
    float rl = v - __uint_as_float(uh << 16);
    uint ul = bf16hi(__float_as_uint(rl));
    return make_uint2(uh, ul);
}

// ---------------------------------------------------------------------------
// Prep (merged): wipe MALL rings to tag=1; zero counters; build A-fragments;
// blocks >= 1024 additionally transpose x -> xT (64x64 LDS tile, coalesced).
// ---------------------------------------------------------------------------
__global__ void lstm_prep(const float* __restrict__ x,
                          const float* __restrict__ w_is,
                          const float* __restrict__ w_ss,
                          float* __restrict__ ws, long long n_ws, int use_xt)
{
    __shared__ float L[64 * 65];
    const long long stride = (long long)gridDim.x * blockDim.x;
    const long long t0 = (long long)blockIdx.x * blockDim.x + threadIdx.x;
    uint* wsu = (uint*)ws;

    for (long long i = t0; i < 524288LL + 32768LL; i += stride) {
        long long a = (i < 524288LL) ? i : (CBX + (i - 524288LL));
        stu_nw(wsu + a, 0x00000001u);
    }
    for (long long i = CNT + t0; i < CNT + 4096; i += stride)
        stu_nw(wsu + i, 0u);

    if (n_ws >= WS_MIN) {
        ushort* af = (ushort*)(ws + AFB);
        for (long long e = t0; e < AF_N; e += stride) {
            int idx   = (int)e;
            int chunk = idx >> 9;           // (g*NRT+rt)*NKT + kt
            int lane  = (idx >> 3) & 63;
            int jj    = idx & 7;
            int g  = chunk / (10 * NKT);
            int rm = chunk % (10 * NKT);
            int rt = rm / NKT, kt = rm % NKT;
            int m = lane & 15, quad = lane >> 4;
            int r = rt * 16 + m;
            int q = r >> 5, hl = r & 31;
            int o = q * HD_ + g * GH + hl;
            int k = kt * 32 + quad * 8 + jj;
            float v;
            if (k < C_)            v = w_is[o * C_ + k];
            else if (k < C_ + HD_) v = w_ss[(o * HD_ + (k - C_)) * 2 + 1];
            else                   v = w_ss[(o * HD_ + (k - C_ - HD_)) * 2 + 0];
            uint uh = bf16hi(__float_as_uint(v));
            float rl = v - __uint_as_float(uh << 16);
            uint ul = bf16hi(__float_as_uint(rl));
            int base = chunk * 1024 + lane * 16 + jj;   // ushort units
            af[base]     = (ushort)uh;
            af[base + 8] = (ushort)ul;
        }
    }

    if (use_xt && blockIdx.x >= 1024) {
        const int bb = blockIdx.x - 1024;
        const int b = bb >> 6, hr = bb & 63;
        const int tid = threadIdx.x;          // 256 threads
        #pragma unroll
        for (int it = 0; it < 16; ++it) {
            int c = it * 4 + (tid >> 6), w = tid & 63;
            L[c * 65 + w] = x[(((size_t)b * C_ + c) * H_ + hr) * W_ + w];
        }
        __syncthreads();
        float* xt = ws + XT;
        #pragma unroll
        for (int it = 0; it < 16; ++it) {
            int w = it * 4 + (tid >> 6), c = tid & 63;
            xt[(((size_t)b * H_ + hr) * W_ + w) * C_ + c] = L[c * 65 + w];
        }
    }
}

// ---------------------------------------------------------------------------
// Post-pass: osc[n][w][hd] -> out[b][hd][hr][w], both sides coalesced.
// ---------------------------------------------------------------------------
__global__ void lstm_oxpose(const float* __restrict__ ws, float* __restrict__ out)
{
    __shared__ float L[64 * 129];
    const int n = blockIdx.x, b = n >> 6, hr = n & 63;
    const float* osc = ws + OSC + (size_t)n * 64 * 128;
    const int tid = threadIdx.x;          // 256 threads
    #pragma unroll
    for (int it = 0; it < 32; ++it) {
        int e = it * 256 + tid;
        int w = e >> 7, hd = e & 127;
        L[w * 129 + hd] = osc[e];
    }
    __syncthreads();
    #pragma unroll
    for (int it = 0; it < 32; ++it) {
        int e = it * 256 + tid;
        int hd = e >> 6, w = e & 63;
        out[(((size_t)b * HD_ + hd) * H_ + hr) * W_ + w] = L[w * 129 + hd];
    }
}

// ---------------------------------------------------------------------------
// Persistent kernel: 127 diagonal steps, self-tagged dataflow, dedup polls.
// Own-slice chunks (ch>>3 == g, cp>=1) are NOT polled: the nonlin waves build
// them via __shfl directly into Bf during the post phase (no MALL roundtrip).
// ---------------------------------------------------------------------------
__global__ void __launch_bounds__(NT, 2) lstm_persist(
    const float* __restrict__ x,
    const float* __restrict__ ws_c,
    const float* __restrict__ b_is,
    const float* __restrict__ b_ss,
    float* __restrict__ out,
    float* __restrict__ ws,
    int use_xt, int use_osc)
{
    __shared__ uint  Bf[NKT * 576];     // B-fragments: per kt, 64 lanes x (16B hi + 16B lo)
    __shared__ float Gp[ROWS * GPS];    // gate panel
    __shared__ float Cs[2][17 * GH];    // double-buffered c panel [colp][hl]
    __shared__ float bias_s[ROWS];

    const int tid = threadIdx.x;
    const int cgp = blockIdx.x >> 2;
    const int g   = blockIdx.x & 3;
    const int n0  = cgp * TC;
    const int inb  = (n0 & 63) != 0;
    const int hasr = ((n0 + TC) & 63) != 0;

    uint* hring = (uint*)ws;
    uint* cring = (uint*)(ws + CBX);
    int*  gcntp = (int*)(ws + GCNT);
    float* osc = ws + OSC;
    const float* xt = ws_c + XT;
    const uint4* afq = (const uint4*)(ws_c + AFB);

    if (tid < ROWS) {
        int q = tid >> 5, hl = tid & 31;
        int o = q * HD_ + g * GH + hl;
        bias_s[tid] = b_is[o] + b_ss[o];
    }
    if (tid < 17 * GH) Cs[0][tid] = 0.f;    // step-0 c panel
    if (tid >= 544 && tid < 544 + GH) Cs[1][tid - 544] = 0.f;   // boundary col, buf 1

    const int lane = tid & 63;
    const int wv   = tid >> 6;          // waves 0-9 = GEMM row-tiles
    const int quad = lane >> 4;
    const int colc = lane & 15;
    uint* bfr = &Bf[lane * 8 + ((lane >> 2) << 2)];   // GEMM read base

    // ---- poll-thread constants (tid < 544): one dwordx4 of the h window ----
    const int cp  = tid >> 5;           // window col 0..16 (global col n0-1+cp)
    const int ch  = tid & 31;           // hd chunk: hd = ch*4
    const int pq  = (ch >> 1) & 3;      // quad of the fragment lane
    const int pj0 = (ch & 1) * 4;       // jj offset (0 or 4)
    const int kta = 2 + (ch >> 3);      // unshifted k-tile (cols n0..n0+15)
    const int laneA = pq * 16 + ((cp >= 1) ? (cp - 1) : 0);
    const int laneB = pq * 16 + ((cp <= 15) ? cp : 0);
    uint* bfA = &Bf[laneA * 8 + ((laneA >> 2) << 2) + kta * 576 + (pj0 >> 1)];
    uint* bfB = &Bf[laneB * 8 + ((laneB >> 2) << 2) + (kta + 4) * 576 + (pj0 >> 1)];
    const uint* hbase = hring + (size_t)(n0 - 1 + cp) * 128 + ch * 4;
    const int pskip = (cp == 0 && !inb);
    const int ownf  = ((ch >> 3) == g) && (cp >= 1);  // built by post-phase shfl

    // ---- x-thread constants (544 <= tid < 672): one lane of kt 0/1 ----
    const int xi = tid - 544;
    const int xkt = xi >> 6, xl = xi & 63;
    const int xq = xl >> 4, xcolc = xl & 15;
    const int xc0 = xkt * 32 + xq * 8;
    const int xn = n0 + xcolc, xb = xn >> 6, xhr = xn & 63;
    uint* bfX = &Bf[xl * 8 + ((xl >> 2) << 2) + xkt * 576];

    const int ci = tid - 672;           // 0..7: c-boundary poll; ==8: WAR wait

    // ---- A hi AND lo fragments pinned in registers (GEMM waves only) ----
    bf16x8 Ahr[NKT], Alr[NKT];
    if (wv < 10) {
        const uint4* ap0 = afq + (size_t)((g * 10 + wv) * NKT) * 128 + lane * 2;
        #pragma unroll
        for (int kt = 0; kt < NKT; ++kt) {
            uint4 ha = ap0[kt * 128];
            Ahr[kt] = *(bf16x8*)&ha;
            asm volatile("" : "+v"(Ahr[kt]));
            uint4 la = ap0[kt * 128 + 1];
            Alr[kt] = *(bf16x8*)&la;
            asm volatile("" : "+v"(Alr[kt]));
        }
    }

    __syncthreads();

    for (int j = 0; j < SW_; ++j) {
        const uint want = ((j - 1) >> 2) & 1u;   // expected tag of step j-1 data
        const uint wtag = (j >> 2) & 1u;         // tag we write at step j

        // ---- P1: build B-fragments (dedup polls; own slice skipped) ----
        if (tid < 544) {
            if (!ownf || j == 0) {               // own slice filled by post-phase
                u32x4 a = {0, 0, 0, 0};
                if (j > 0 && !pskip)
                    poll1(hbase + (size_t)((j - 1) & 3) * HSLOT, want, a);
                uint2 e0 = splitbf(__uint_as_float(a[0]));
                uint2 e1 = splitbf(__uint_as_float(a[1]));
                uint2 e2 = splitbf(__uint_as_float(a[2]));
                uint2 e3 = splitbf(__uint_as_float(a[3]));
                u32x2 hp = {e0.x | (e1.x << 16), e2.x | (e3.x << 16)};
                u32x2 lp = {e0.y | (e1.y << 16), e2.y | (e3.y << 16)};
                if (cp >= 1)  { *(u32x2*)bfA = hp; *(u32x2*)(bfA + 4) = lp; }
                if (cp <= 15) { *(u32x2*)bfB = hp; *(u32x2*)(bfB + 4) = lp; }
            }
        } else if (tid < 672) {
            float xv[8];
            int w = j - xhr;
            if ((unsigned)w < (unsigned)W_) {
                if (use_xt) {
                    const float* xp = xt + (((size_t)xb * H_ + xhr) * W_ + w) * C_ + xc0;
                    f32x4 va = *(const f32x4*)xp, vb = *(const f32x4*)(xp + 4);
                    #pragma unroll
                    for (int r = 0; r < 4; ++r) { xv[r] = va[r]; xv[4 + r] = vb[r]; }
                } else {
                    #pragma unroll
                    for (int r = 0; r < 8; ++r)
                        xv[r] = x[(((size_t)xb * C_ + xc0 + r) * H_ + xhr) * W_ + w];
                }
            } else {
                #pragma unroll
                for (int r = 0; r < 8; ++r) xv[r] = 0.f;
            }
            uint hw[4], lw[4];
            #pragma unroll
            for (int p = 0; p < 4; ++p) {
                uint2 e0 = splitbf(xv[2 * p]), e1 = splitbf(xv[2 * p + 1]);
                hw[p] = e0.x | (e1.x << 16);
                lw[p] = e0.y | (e1.y << 16);
            }
            *(uint4*)bfX       = make_uint4(hw[0], hw[1], hw[2], hw[3]);
            *(uint4*)(bfX + 4) = make_uint4(lw[0], lw[1], lw[2], lw[3]);
        } else if (ci >= 0 && ci < 8) {              // c-boundary poll (32 floats)
            if (inb && j > 0) {
                u32x4 cv;
                const uint* cpx = cring +
                    (((size_t)((j - 1) & 3) * NCG + (cgp - 1)) * NG + g) * GH + ci * 4;
                poll1(cpx, want, cv);
                #pragma unroll
                for (int r = 0; r < 4; ++r)
                    Cs[j & 1][ci * 4 + r] = __uint_as_float(cv[r]);
            }
        } else if (ci == 8) {                        // WAR: right cluster read j-3
            if (j >= 4 && hasr) wait_ge(gcntp + (cgp + 1) * 32, 4 * (j - 2));
        }
        __syncthreads();                             // sync_a: Bf/Cs ready
        if (tid == 0) rbump(gcntp + cgp * 32);       // our step-(j-1) reads done

        // ---- GEMM: rows [wv*16,+16) x 16 cols, K=320, 2 acc chains ----
        if (wv < 10) {
            f32x4 acc0 = {0.f, 0.f, 0.f, 0.f};
            f32x4 acc1 = {0.f, 0.f, 0.f, 0.f};
            __builtin_amdgcn_s_setprio(1);
            #pragma unroll
            for (int kt = 0; kt < NKT; kt += 2) {
                const uint* bp0 = bfr + kt * 576;
                uint4 hb0 = *(const uint4*)bp0;
                uint4 lb0 = *(const uint4*)(bp0 + 4);
                const uint* bp1 = bfr + (kt + 1) * 576;
                uint4 hb1 = *(const uint4*)bp1;
                uint4 lb1 = *(const uint4*)(bp1 + 4);
                bf16x8 Bh0 = *(bf16x8*)&hb0, Bl0 = *(bf16x8*)&lb0;
                bf16x8 Bh1 = *(bf16x8*)&hb1, Bl1 = *(bf16x8*)&lb1;
                acc0 = __builtin_amdgcn_mfma_f32_16x16x32_bf16(Ahr[kt],     Bh0, acc0, 0, 0, 0);
                acc1 = __builtin_amdgcn_mfma_f32_16x16x32_bf16(Ahr[kt + 1], Bh1, acc1, 0, 0, 0);
                acc0 = __builtin_amdgcn_mfma_f32_16x16x32_bf16(Ahr[kt],     Bl0, acc0, 0, 0, 0);
                acc1 = __builtin_amdgcn_mfma_f32_16x16x32_bf16(Ahr[kt + 1], Bl1, acc1, 0, 0, 0);
                acc0 = __builtin_amdgcn_mfma_f32_16x16x32_bf16(Alr[kt],     Bh0, acc0, 0, 0, 0);
                acc1 = __builtin_amdgcn_mfma_f32_16x16x32_bf16(Alr[kt + 1], Bh1, acc1, 0, 0, 0);
                acc0 = __builtin_amdgcn_mfma_f32_16x16x32_bf16(Alr[kt],     Bl0, acc0, 0, 0, 0);
                acc1 = __builtin_amdgcn_mfma_f32_16x16x32_bf16(Alr[kt + 1], Bl1, acc1, 0, 0, 0);
            }
            __builtin_amdgcn_s_setprio(0);
            #pragma unroll
            for (int r = 0; r < 4; ++r)
                Gp[(wv * 16 + quad * 4 + r) * GPS + colc] = acc0[r] + acc1[r];
        }
        __syncthreads();                             // sync_b: gates ready

        // ---- post: nonlin + state + ring stores + own-slice Bf build ----
        if (tid < GH * TC) {
            const int hl = tid & 31, col = tid >> 5;
            int n = n0 + col, b = n >> 6, hr = n & 63;
            float go  = Gp[(0 * GH + hl) * GPS + col] + bias_s[0 * GH + hl];
            float gfl = Gp[(1 * GH + hl) * GPS + col] + bias_s[1 * GH + hl];
            float gfu = Gp[(2 * GH + hl) * GPS + col] + bias_s[2 * GH + hl];
            float gi  = Gp[(3 * GH + hl) * GPS + col] + bias_s[3 * GH + hl];
            float gg  = Gp[(4 * GH + hl) * GPS + col] + bias_s[4 * GH + hl];
            float so = sigm(go), sfl = sigm(gfl), sfu = sigm(gfu), si = sigm(gi);
            float tg = tanh_fast(gg);
            float cp_ = Cs[j & 1][(col + 1) * GH + hl];
            float cs = Cs[j & 1][col * GH + hl];
            float cv = sfl * cp_ + sfu * cs + si * tg;
            float hv = so * tanh_fast(cv);
            Cs[(j + 1) & 1][(col + 1) * GH + hl] = cv;   // disjoint from boundary [0,32)

            // ---- own-slice B-fragments for step j+1 via wave shuffle ----
            // Chunk (colx = 2wv + rr>>3, ch4 = rr&7) gathers h from lanes
            // sb..sb+3; mapping identical to the P1 writer's (kt = 2+g / 6+g).
            uint hvu = __float_as_uint(hv);
            int rr = lane & 15;
            int sb = ((rr >> 3) << 5) + (rr & 7) * 4;
            uint u0 = (uint)__shfl((int)hvu, sb + 0);
            uint u1 = (uint)__shfl((int)hvu, sb + 1);
            uint u2 = (uint)__shfl((int)hvu, sb + 2);
            uint u3 = (uint)__shfl((int)hvu, sb + 3);
            if (lane < 16) {
                int colx = (tid >> 5) + (rr >> 3);       // tid>>5 == 2wv for lane<16
                int ch4 = rr & 7;
                int pq2 = (ch4 >> 1) & 3;
                int pjw = (ch4 & 1) * 2;
                uint2 e0 = splitbf(__uint_as_float(u0));
                uint2 e1 = splitbf(__uint_as_float(u1));
                uint2 e2 = splitbf(__uint_as_float(u2));
                uint2 e3 = splitbf(__uint_as_float(u3));
                u32x2 hp = {e0.x | (e1.x << 16), e2.x | (e3.x << 16)};
                u32x2 lp = {e0.y | (e1.y << 16), e2.y | (e3.y << 16)};
                int lA = pq2 * 16 + colx;
                uint* wA = &Bf[lA * 8 + ((lA >> 2) << 2) + (2 + g) * 576 + pjw];
                *(u32x2*)wA = hp; *(u32x2*)(wA + 4) = lp;
                if (colx <= 14) {
                    int lB = pq2 * 16 + colx + 1;
                    uint* wB = &Bf[lB * 8 + ((lB >> 2) << 2) + (6 + g) * 576 + pjw];
                    *(u32x2*)wB = hp; *(u32x2*)(wB + 4) = lp;
                }
            }

            uint pk = (hvu & ~1u) | wtag;               // tag in fp32 LSB: 2^-24
            uint other = (uint)__shfl_xor((int)pk, 1);
            if (!(hl & 1)) {                            // paired store: 2 hd per req
                u32x2 pv = {pk, other};
                st2_nw(hring + (size_t)(j & 3) * HSLOT + (size_t)n * 128 + g * GH + (hl & ~1), pv);
            }
            if (col == TC - 1) {
                uint cpk = (__float_as_uint(cv) & ~1u) | wtag;
                stu_nw(cring + (((size_t)(j & 3) * NCG + cgp) * NG + g) * GH + hl, cpk);
            }
            int w = j - hr;
            if ((unsigned)w < (unsigned)W_) {
                if (use_osc)                             // 128B-contiguous lines
                    osc[((size_t)n * 64 + w) * 128 + g * GH + hl] = hv;
                else
                    out[(((size_t)b * HD_ + g * GH + hl) * H_ + hr) * W_ + w] = hv;
            }
        }
        // no third barrier: Bf rewrite (next P1 / this post) is fenced by
        // sync_b (GEMM reads done) and next sync_a (before next GEMM reads);
        // own-slice writes are disjoint from P1's partner chunks (different kt).
    }
}

// ---------------------------------------------------------------------------
extern "C" void kernel_launch(void* const* d_in, const int* in_sizes, int n_in,
                              void* d_out, int out_size, void* d_ws, size_t ws_size,
                              hipStream_t stream)
{
    const float* x    = (const float*)d_in[0];
    const float* w_is = (const float*)d_in[1];
    const float* b_is = (const float*)d_in[2];
    const float* w_ss = (const float*)d_in[3];
    const float* b_ss = (const float*)d_in[4];
    float* out = (float*)d_out;
    float* ws  = (float*)d_ws;

    const long long n_ws = (long long)(ws_size / 4);
    const int use_xt  = (n_ws >= WS_XT)  ? 1 : 0;
    const int use_osc = (n_ws >= WS_OSC) ? 1 : 0;

    hipLaunchKernelGGL(lstm_prep, dim3(2048), dim3(256), 0, stream,
                       x, w_is, w_ss, ws, n_ws, use_xt);

    hipLaunchKernelGGL(lstm_persist, dim3(NG * NCG), dim3(NT), 0, stream,
                       x, ws, b_is, b_ss, out, ws, use_xt, use_osc);

    if (use_osc)
        hipLaunchKernelGGL(lstm_oxpose, dim3(1024), dim3(256), 0, stream, ws, out);
}